// Round 7
// baseline (611.305 us; speedup 1.0000x reference)
//
#include <hip/hip_runtime.h>

// Problem constants (fixed by reference)
#define N_SRC   100000
#define N_DSTC  50000
#define N_EDGES 1000000
#define DIM     64
#define NCLS    64

#define SCAN_BPB 256                                   // bins per scan block
#define SCAN_NB  ((N_DSTC + SCAN_BPB - 1) / SCAN_BPB)  // 196

#define HIST_BLOCKS ((N_EDGES / 4 + 255) / 256)        // 977
#define REG_BLOCKS  1024
#define GATHER_GRID 2048

// ws layout (4-byte slots), zero region = [0, 50130):
//   hist    [0, 50000)        int
//   colsum  [50000, 50064)    float
//   regA    [50064]           float   Sum (u*x)^2
//   regB    [50065, 50129)    float   Sum_r u_r * x[r][c]
//   doneG   [50129]           int
//   blockSums [50130, 50326)  int   (fully written by scan_local)
//   cursor    [50326, 100326) int   (fully written by scan chain)
//   sorted_src[100326, 1100326) int (fully written by reorder)
//   xh (bf16 x copy) at 16B-aligned 1100328 .. +3200000 ints
//     (100000*64 ushort, fully written by hist_reg reg-blocks)

// ---------------------------------------------------------------------------
// K1: fused histogram (blocks [0,HIST_BLOCKS)) + reg A/B accumulation +
// bf16-x conversion (blocks [HIST_BLOCKS, HIST_BLOCKS+REG_BLOCKS)).
__global__ __launch_bounds__(256) void hist_reg_kernel(
    const int4*  __restrict__ dst4,
    const float* __restrict__ x,
    const float* __restrict__ u_sum,
    int*   __restrict__ hist,
    float* __restrict__ regA,
    float* __restrict__ regB,
    unsigned short* __restrict__ xh) {
  __shared__ float redB[4][64];
  __shared__ float redA[4];

  if (blockIdx.x < HIST_BLOCKS) {
    int i = blockIdx.x * blockDim.x + threadIdx.x;
    if (i < N_EDGES / 4) {
      int4 d = dst4[i];
      atomicAdd(&hist[d.x], 1);
      atomicAdd(&hist[d.y], 1);
      atomicAdd(&hist[d.z], 1);
      atomicAdd(&hist[d.w], 1);
    }
    return;
  }

  // reg part: lane owns column c = lane. Also emit bf16 copy of x (RNE).
  const int tid  = threadIdx.x;
  const int wv   = tid >> 6;
  const int lane = tid & 63;
  const int waveId     = (blockIdx.x - HIST_BLOCKS) * 4 + wv;
  const int totalWaves = REG_BLOCKS * 4;

  float accA = 0.0f;
  float accB = 0.0f;
  for (int r = waveId; r < N_SRC; r += totalWaves) {
    float u  = u_sum[r];                 // wave-uniform -> broadcast
    float xv = x[r * DIM + lane];
    // bf16 round-to-nearest-even
    unsigned int b = __float_as_uint(xv);
    unsigned int rn = (b + 0x7fffu + ((b >> 16) & 1u)) >> 16;
    xh[r * DIM + lane] = (unsigned short)rn;
    float t  = u * xv;
    accB += t;
    accA = fmaf(t, t, accA);
  }
  #pragma unroll
  for (int off = 32; off > 0; off >>= 1)
    accA += __shfl_down(accA, off, 64);
  if (lane == 0) redA[wv] = accA;
  redB[wv][lane] = accB;
  __syncthreads();
  if (tid < 64) {
    float b = redB[0][tid] + redB[1][tid] + redB[2][tid] + redB[3][tid];
    atomicAdd(&regB[tid], b);
  }
  if (tid == 0) {
    float a = redA[0] + redA[1] + redA[2] + redA[3];
    atomicAdd(regA, a);
  }
}

// ---------------------------------------------------------------------------
// K2a: per-block exclusive scan of 256 bins; emit block totals.
__global__ __launch_bounds__(256) void scan_local(
    const int* __restrict__ hist, int* __restrict__ cursor,
    int* __restrict__ blockSums) {
  __shared__ int A[256], B[256];
  const int b = blockIdx.x, t = threadIdx.x;
  const int g = b * SCAN_BPB + t;
  int v = (g < N_DSTC) ? hist[g] : 0;
  A[t] = v;
  __syncthreads();
  int* cur = A; int* nxt = B;
  for (int off = 1; off < 256; off <<= 1) {
    int s = cur[t] + ((t >= off) ? cur[t - off] : 0);
    nxt[t] = s;
    __syncthreads();
    int* tmp = cur; cur = nxt; nxt = tmp;
  }
  if (g < N_DSTC) cursor[g] = cur[t] - v;   // exclusive within block
  if (t == 255) blockSums[b] = cur[255];
}

// K2b: each block redundantly scans the 196 block totals in LDS, then adds
// its own block offset to its 256 cursor entries.
__global__ __launch_bounds__(256) void scan_addoff(
    int* __restrict__ cursor, const int* __restrict__ blockSums) {
  __shared__ int A[256], B[256];
  const int b = blockIdx.x, t = threadIdx.x;
  A[t] = (t < SCAN_NB) ? blockSums[t] : 0;
  __syncthreads();
  int* cur = A; int* nxt = B;
  for (int off = 1; off < 256; off <<= 1) {
    int s = cur[t] + ((t >= off) ? cur[t - off] : 0);
    nxt[t] = s;
    __syncthreads();
    int* tmp = cur; cur = nxt; nxt = tmp;
  }
  int off = (b > 0) ? cur[b - 1] : 0;   // exclusive offset of block b
  int g = b * SCAN_BPB + t;
  if (g < N_DSTC) cursor[g] += off;
}

// ---------------------------------------------------------------------------
// K3: counting-sort pass 2, int4-vectorized. After this kernel,
// cursor[i] == end offset of bin i.
__global__ __launch_bounds__(256) void reorder_kernel(
    const int4* __restrict__ src4, const int4* __restrict__ dst4,
    int* __restrict__ cursor, int* __restrict__ sorted_src) {
  int i = blockIdx.x * blockDim.x + threadIdx.x;
  if (i < N_EDGES / 4) {
    int4 s = src4[i];
    int4 d = dst4[i];
    int p0 = atomicAdd(&cursor[d.x], 1); sorted_src[p0] = s.x;
    int p1 = atomicAdd(&cursor[d.y], 1); sorted_src[p1] = s.y;
    int p2 = atomicAdd(&cursor[d.z], 1); sorted_src[p2] = s.z;
    int p3 = atomicAdd(&cursor[d.w], 1); sorted_src[p3] = s.w;
  }
}

// ---------------------------------------------------------------------------
// bf16 pair -> two floats (bit shift; bf16 is the top half of f32)
__device__ __forceinline__ float bflo(unsigned int w) {
  return __uint_as_float(w << 16);
}
__device__ __forceinline__ float bfhi(unsigned int w) {
  return __uint_as_float(w & 0xffff0000u);
}

// ---------------------------------------------------------------------------
// K4: fused gather (bf16 x) + mean + GEMV + colsum + last-block reg combine.
// One dst row per wave; es = lane>>3 edge subgroup (8), q = lane&7 (16B slot
// of the 128B bf16 row). 16 edges per full step, 2 loads in flight per lane.
__global__ __launch_bounds__(256, 4) void gather_h(
    const float* __restrict__ x,
    const unsigned short* __restrict__ xh,
    const float* __restrict__ Ww,   // [64][128]
    const float* __restrict__ Wb,   // [64]
    const int*   __restrict__ cursor,      // end offsets after reorder
    const int*   __restrict__ sorted_src,
    float* __restrict__ h,
    float* __restrict__ colsum,
    float* __restrict__ regA,
    float* __restrict__ regB,
    int*   __restrict__ doneG,
    float* __restrict__ out_scalar) {
  __shared__ float Wt[2 * DIM][NCLS + 1];  // Wt[k][c] = Ww[c*128+k]
  __shared__ float colred[4][64];
  __shared__ int   lastFlag;

  const int tid = threadIdx.x;
  for (int idx = tid; idx < NCLS * 2 * DIM; idx += 256) {
    int c = idx >> 7, k = idx & 127;
    Wt[k][c] = Ww[idx];
  }
  __syncthreads();

  const int wv   = tid >> 6;
  const int lane = tid & 63;
  const int es   = lane >> 3;   // 8 edge subgroups
  const int q    = lane & 7;    // 16B slot within 128B row
  const int waveId = blockIdx.x * 4 + wv;
  const int tw     = gridDim.x * 4;
  const float bias = Wb[lane];
  const uint4* xh4 = reinterpret_cast<const uint4*>(xh);  // 8 uint4 per row

  float colacc = 0.0f;

  for (int r = waveId; r < N_DSTC; r += tw) {
    int beg = (r == 0) ? 0 : cursor[r - 1];
    int end = cursor[r];
    int cnt = end - beg;

    float a0 = 0.f, a1 = 0.f, a2 = 0.f, a3 = 0.f,
          a4 = 0.f, a5 = 0.f, a6 = 0.f, a7 = 0.f;
    for (int base = 0; base < cnt; base += 64) {
      int rem = cnt - base;
      int mm  = rem < 64 ? rem : 64;
      int idxv = (lane < rem) ? sorted_src[beg + base + lane] : 0;

      int jb = 0;
      for (; jb + 16 <= mm; jb += 16) {  // 2 gathers in flight per lane
        int s0 = __shfl(idxv, jb + es,     64);
        int s1 = __shfl(idxv, jb + 8 + es, 64);
        uint4 w0 = xh4[s0 * 8 + q];
        uint4 w1 = xh4[s1 * 8 + q];
        a0 += bflo(w0.x) + bflo(w1.x);  a1 += bfhi(w0.x) + bfhi(w1.x);
        a2 += bflo(w0.y) + bflo(w1.y);  a3 += bfhi(w0.y) + bfhi(w1.y);
        a4 += bflo(w0.z) + bflo(w1.z);  a5 += bfhi(w0.z) + bfhi(w1.z);
        a6 += bflo(w0.w) + bflo(w1.w);  a7 += bfhi(w0.w) + bfhi(w1.w);
      }
      for (; jb < mm; jb += 8) {         // tail: predicated, uniform shfl
        int j = jb + es;
        int s0 = __shfl(idxv, j & 63, 64);
        if (j < mm) {
          uint4 w0 = xh4[s0 * 8 + q];
          a0 += bflo(w0.x);  a1 += bfhi(w0.x);
          a2 += bflo(w0.y);  a3 += bfhi(w0.y);
          a4 += bflo(w0.z);  a5 += bfhi(w0.z);
          a6 += bflo(w0.w);  a7 += bfhi(w0.w);
        }
      }
    }
    // reduce across the 8 edge subgroups (xor 8,16,32)
    #pragma unroll
    for (int off = 8; off < 64; off <<= 1) {
      a0 += __shfl_xor(a0, off, 64); a1 += __shfl_xor(a1, off, 64);
      a2 += __shfl_xor(a2, off, 64); a3 += __shfl_xor(a3, off, 64);
      a4 += __shfl_xor(a4, off, 64); a5 += __shfl_xor(a5, off, 64);
      a6 += __shfl_xor(a6, off, 64); a7 += __shfl_xor(a7, off, 64);
    }
    // redistribute: lane c takes component (c&7) from lane (c>>3)
    // (lane L holds columns (L&7)*8 + j in a_j after the reduce)
    const int srcl = lane >> 3;
    float t0 = __shfl(a0, srcl, 64), t1 = __shfl(a1, srcl, 64);
    float t2 = __shfl(a2, srcl, 64), t3 = __shfl(a3, srcl, 64);
    float t4 = __shfl(a4, srcl, 64), t5 = __shfl(a5, srcl, 64);
    float t6 = __shfl(a6, srcl, 64), t7 = __shfl(a7, srcl, 64);
    const int sel = lane & 7;
    float ysum = t0;
    ysum = (sel == 1) ? t1 : ysum;  ysum = (sel == 2) ? t2 : ysum;
    ysum = (sel == 3) ? t3 : ysum;  ysum = (sel == 4) ? t4 : ysum;
    ysum = (sel == 5) ? t5 : ysum;  ysum = (sel == 6) ? t6 : ysum;
    ysum = (sel == 7) ? t7 : ysum;

    float ym = ysum / fmaxf((float)cnt, 1.0f);   // lane == column
    colacc += ym;

    float xv = x[r * DIM + lane];                 // f32 x_dst, coalesced

    float hacc = bias;
    #pragma unroll
    for (int k = 0; k < DIM; ++k) {
      float fx = __shfl(xv, k, 64);
      float fy = __shfl(ym, k, 64);
      hacc = fmaf(fx, Wt[k][lane], hacc);
      hacc = fmaf(fy, Wt[DIM + k][lane], hacc);
    }
    h[r * NCLS + lane] = hacc;
  }

  colred[wv][lane] = colacc;
  __syncthreads();
  if (tid < 64) {
    float s = colred[0][tid] + colred[1][tid] + colred[2][tid] + colred[3][tid];
    atomicAdd(&colsum[tid], s);
  }

  // ---- last-block reg-loss combine ----
  __syncthreads();
  if (tid == 0) {
    __threadfence();
    int old = atomicAdd(doneG, 1);
    lastFlag = (old == (int)gridDim.x - 1) ? 1 : 0;
  }
  __syncthreads();
  if (lastFlag && tid < 64) {
    const float inv_nd = 1.0f / (float)N_DSTC;
    float cs = atomicAdd(&colsum[tid], 0.0f);   // coherent atomic read
    float bv = atomicAdd(&regB[tid], 0.0f);
    float mx = cs * inv_nd;
    float p = fmaf((float)N_SRC * mx, mx, -2.0f * inv_nd * mx * bv);
    #pragma unroll
    for (int off = 32; off > 0; off >>= 1)
      p += __shfl_down(p, off, 64);
    if (tid == 0) {
      float av = atomicAdd(regA, 0.0f);
      float total = fmaf(av, inv_nd * inv_nd, p);
      out_scalar[0] = total * (1.0f / ((float)N_SRC * (float)NCLS));
    }
  }
}

// ---------------------------------------------------------------------------
extern "C" void kernel_launch(void* const* d_in, const int* in_sizes, int n_in,
                              void* d_out, int out_size, void* d_ws, size_t ws_size,
                              hipStream_t stream) {
  const float* x     = (const float*)d_in[0];
  // d_in[1] = w : dead (only ones_like(w) is used)
  const float* u_sum = (const float*)d_in[2];
  const float* Ww    = (const float*)d_in[3];
  const float* Wb    = (const float*)d_in[4];
  const int*   src   = (const int*)d_in[5];
  const int*   dst   = (const int*)d_in[6];

  float* out = (float*)d_out;
  int*   wsI = (int*)d_ws;

  int*   hist       = wsI;                        // 50000
  float* colsum     = (float*)(wsI + N_DSTC);     // 64
  float* regA       = colsum + 64;                // 1
  float* regB       = regA + 1;                   // 64
  int*   doneG      = (int*)(regB + 64);          // 1
  int*   blockSums  = doneG + 1;                  // 196
  int*   cursor     = blockSums + SCAN_NB;        // 50000
  int*   sorted_src = cursor + N_DSTC;            // 1,000,000
  // 16B-aligned bf16 x copy
  unsigned short* xh = (unsigned short*)(wsI + 1100328);

  // zero: hist + colsum + regA + regB + doneG
  hipMemsetAsync(d_ws, 0, (size_t)(N_DSTC + 64 + 1 + 64 + 1) * sizeof(int), stream);

  hist_reg_kernel<<<HIST_BLOCKS + REG_BLOCKS, 256, 0, stream>>>(
      (const int4*)dst, x, u_sum, hist, regA, regB, xh);
  scan_local  <<<SCAN_NB, 256, 0, stream>>>(hist, cursor, blockSums);
  scan_addoff <<<SCAN_NB, 256, 0, stream>>>(cursor, blockSums);
  reorder_kernel<<<(N_EDGES / 4 + 255) / 256, 256, 0, stream>>>(
      (const int4*)src, (const int4*)dst, cursor, sorted_src);
  gather_h    <<<GATHER_GRID, 256, 0, stream>>>(
      x, xh, Ww, Wb, cursor, sorted_src, out, colsum, regA, regB, doneG,
      out + (size_t)N_DSTC * NCLS);
}

// Round 8
// 422.201 us; speedup vs baseline: 1.4479x; 1.4479x over previous
//
#include <hip/hip_runtime.h>

// Problem constants (fixed by reference)
#define N_SRC   100000
#define N_DSTC  50000
#define N_EDGES 1000000
#define DIM     64
#define NCLS    64

#define SCAN_BPB 256                                   // bins per scan block
#define SCAN_NB  ((N_DSTC + SCAN_BPB - 1) / SCAN_BPB)  // 196

#define HIST_BLOCKS ((N_EDGES / 4 + 255) / 256)        // 977
#define REG_BLOCKS  1024
#define GATHER_GRID 2048

// ws layout (4-byte slots), zero region = [0, 50130):
//   hist    [0, 50000)        int
//   colsum  [50000, 50064)    float
//   regA    [50064]           float   Sum (u*x)^2
//   regB    [50065, 50129)    float   Sum_r u_r * x[r][c]
//   doneG   [50129]           int
//   blockSums [50130, 50326)  int   (fully written by scan_local)
//   cursor    [50326, 100326) int   (fully written by scan chain)
//   sorted_src[100326, 1100326) int (fully written by reorder)
//   xh (bf16 x copy) at int offset 1100328 (16B aligned), 6.4M ushort
//     (fully written by hist blocks of K1 every launch)

__device__ __forceinline__ unsigned int bf16rne(float f) {
  unsigned int b = __float_as_uint(f);
  return (b + 0x7fffu + ((b >> 16) & 1u)) >> 16;
}
__device__ __forceinline__ float bflo(unsigned int w) {
  return __uint_as_float(w << 16);
}
__device__ __forceinline__ float bfhi(unsigned int w) {
  return __uint_as_float(w & 0xffff0000u);
}

// ---------------------------------------------------------------------------
// K1: fused histogram + bf16-x conversion (blocks [0,HIST_BLOCKS)) and
// reg A/B accumulation (blocks [HIST_BLOCKS, HIST_BLOCKS+REG_BLOCKS)).
__global__ __launch_bounds__(256) void hist_reg_kernel(
    const int4*  __restrict__ dst4,
    const float* __restrict__ x,
    const float* __restrict__ u_sum,
    int*   __restrict__ hist,
    float* __restrict__ regA,
    float* __restrict__ regB,
    uint2* __restrict__ xh2) {
  __shared__ float redB[4][64];
  __shared__ float redA[4];

  if (blockIdx.x < HIST_BLOCKS) {
    int i = blockIdx.x * blockDim.x + threadIdx.x;
    if (i < N_EDGES / 4) {
      int4 d = dst4[i];
      atomicAdd(&hist[d.x], 1);
      atomicAdd(&hist[d.y], 1);
      atomicAdd(&hist[d.z], 1);
      atomicAdd(&hist[d.w], 1);
    }
    // bf16 conversion: 1.6M float4 -> uint2, strided over hist blocks
    const float4* x4 = reinterpret_cast<const float4*>(x);
    const int nv = N_SRC * DIM / 4;
    for (int j = blockIdx.x * blockDim.x + threadIdx.x; j < nv;
         j += HIST_BLOCKS * 256) {
      float4 v = x4[j];
      unsigned int lo = (bf16rne(v.y) << 16) | bf16rne(v.x);
      unsigned int hi = (bf16rne(v.w) << 16) | bf16rne(v.z);
      xh2[j] = make_uint2(lo, hi);
    }
    return;
  }

  // reg part: lane owns column c = lane (pure f32).
  const int tid  = threadIdx.x;
  const int wv   = tid >> 6;
  const int lane = tid & 63;
  const int waveId     = (blockIdx.x - HIST_BLOCKS) * 4 + wv;
  const int totalWaves = REG_BLOCKS * 4;

  float accA = 0.0f;
  float accB = 0.0f;
  for (int r = waveId; r < N_SRC; r += totalWaves) {
    float u  = u_sum[r];                 // wave-uniform -> broadcast
    float xv = x[r * DIM + lane];
    float t  = u * xv;
    accB += t;
    accA = fmaf(t, t, accA);
  }
  #pragma unroll
  for (int off = 32; off > 0; off >>= 1)
    accA += __shfl_down(accA, off, 64);
  if (lane == 0) redA[wv] = accA;
  redB[wv][lane] = accB;
  __syncthreads();
  if (tid < 64) {
    float b = redB[0][tid] + redB[1][tid] + redB[2][tid] + redB[3][tid];
    atomicAdd(&regB[tid], b);
  }
  if (tid == 0) {
    float a = redA[0] + redA[1] + redA[2] + redA[3];
    atomicAdd(regA, a);
  }
}

// ---------------------------------------------------------------------------
// K2a: per-block exclusive scan of 256 bins; emit block totals.
__global__ __launch_bounds__(256) void scan_local(
    const int* __restrict__ hist, int* __restrict__ cursor,
    int* __restrict__ blockSums) {
  __shared__ int A[256], B[256];
  const int b = blockIdx.x, t = threadIdx.x;
  const int g = b * SCAN_BPB + t;
  int v = (g < N_DSTC) ? hist[g] : 0;
  A[t] = v;
  __syncthreads();
  int* cur = A; int* nxt = B;
  for (int off = 1; off < 256; off <<= 1) {
    int s = cur[t] + ((t >= off) ? cur[t - off] : 0);
    nxt[t] = s;
    __syncthreads();
    int* tmp = cur; cur = nxt; nxt = tmp;
  }
  if (g < N_DSTC) cursor[g] = cur[t] - v;   // exclusive within block
  if (t == 255) blockSums[b] = cur[255];
}

// K2b: each block redundantly scans the 196 block totals in LDS, then adds
// its own block offset to its 256 cursor entries.
__global__ __launch_bounds__(256) void scan_addoff(
    int* __restrict__ cursor, const int* __restrict__ blockSums) {
  __shared__ int A[256], B[256];
  const int b = blockIdx.x, t = threadIdx.x;
  A[t] = (t < SCAN_NB) ? blockSums[t] : 0;
  __syncthreads();
  int* cur = A; int* nxt = B;
  for (int off = 1; off < 256; off <<= 1) {
    int s = cur[t] + ((t >= off) ? cur[t - off] : 0);
    nxt[t] = s;
    __syncthreads();
    int* tmp = cur; cur = nxt; nxt = tmp;
  }
  int off = (b > 0) ? cur[b - 1] : 0;   // exclusive offset of block b
  int g = b * SCAN_BPB + t;
  if (g < N_DSTC) cursor[g] += off;
}

// ---------------------------------------------------------------------------
// K3: counting-sort pass 2, int4-vectorized. After this kernel,
// cursor[i] == end offset of bin i.
__global__ __launch_bounds__(256) void reorder_kernel(
    const int4* __restrict__ src4, const int4* __restrict__ dst4,
    int* __restrict__ cursor, int* __restrict__ sorted_src) {
  int i = blockIdx.x * blockDim.x + threadIdx.x;
  if (i < N_EDGES / 4) {
    int4 s = src4[i];
    int4 d = dst4[i];
    int p0 = atomicAdd(&cursor[d.x], 1); sorted_src[p0] = s.x;
    int p1 = atomicAdd(&cursor[d.y], 1); sorted_src[p1] = s.y;
    int p2 = atomicAdd(&cursor[d.z], 1); sorted_src[p2] = s.z;
    int p3 = atomicAdd(&cursor[d.w], 1); sorted_src[p3] = s.w;
  }
}

// ---------------------------------------------------------------------------
// K4: fused gather (bf16 rows) + mean + GEMV + colsum + last-block combine.
// R4-exact concurrency: es = lane>>4 (4 edge subgroups), q = lane&15
// (8B slot of the 128B bf16 row), 1-deep, grid 2048. Lane q holds columns
// 4q..4q+3 in a.{x,y,z,w} -- same layout as R4's float4 quadrants.
__global__ __launch_bounds__(256, 4) void gather_h(
    const float* __restrict__ x,
    const uint2* __restrict__ xh2,  // 16 uint2 per 64-col bf16 row
    const float* __restrict__ Ww,   // [64][128]
    const float* __restrict__ Wb,   // [64]
    const int*   __restrict__ cursor,      // end offsets after reorder
    const int*   __restrict__ sorted_src,
    float* __restrict__ h,
    float* __restrict__ colsum,
    float* __restrict__ regA,
    float* __restrict__ regB,
    int*   __restrict__ doneG,
    float* __restrict__ out_scalar) {
  __shared__ float Wt[2 * DIM][NCLS + 1];  // Wt[k][c] = Ww[c*128+k]
  __shared__ float colred[4][64];
  __shared__ int   lastFlag;

  const int tid = threadIdx.x;
  for (int idx = tid; idx < NCLS * 2 * DIM; idx += 256) {
    int c = idx >> 7, k = idx & 127;
    Wt[k][c] = Ww[idx];
  }
  __syncthreads();

  const int wv   = tid >> 6;
  const int lane = tid & 63;
  const int es   = lane >> 4;
  const int q    = lane & 15;
  const int waveId = blockIdx.x * 4 + wv;
  const int tw     = gridDim.x * 4;
  const float bias = Wb[lane];
  const float4* x4 = reinterpret_cast<const float4*>(x);

  float4 colacc = make_float4(0.f, 0.f, 0.f, 0.f);

  for (int r = waveId; r < N_DSTC; r += tw) {
    int beg = (r == 0) ? 0 : cursor[r - 1];
    int end = cursor[r];
    int cnt = end - beg;

    float4 a = make_float4(0.f, 0.f, 0.f, 0.f);
    for (int base = 0; base < cnt; base += 64) {
      int rem = cnt - base;
      int mm  = rem < 64 ? rem : 64;
      int idxv = (lane < rem) ? sorted_src[beg + base + lane] : 0;

      int jb = 0;
      for (; jb + 4 <= mm; jb += 4) {    // R4-exact: 1 row in flight per sg
        int s0 = __shfl(idxv, jb + es, 64);
        uint2 w = xh2[s0 * 16 + q];
        a.x += bflo(w.x);  a.y += bfhi(w.x);
        a.z += bflo(w.y);  a.w += bfhi(w.y);
      }
      for (; jb < mm; jb += 4) {         // tail: predicated, uniform shfl
        int j = jb + es;
        int s0 = __shfl(idxv, j & 63, 64);
        if (j < mm) {
          uint2 w = xh2[s0 * 16 + q];
          a.x += bflo(w.x);  a.y += bfhi(w.x);
          a.z += bflo(w.y);  a.w += bfhi(w.y);
        }
      }
    }
    // reduce across the 4 edge subgroups
    a.x += __shfl_xor(a.x, 16, 64); a.y += __shfl_xor(a.y, 16, 64);
    a.z += __shfl_xor(a.z, 16, 64); a.w += __shfl_xor(a.w, 16, 64);
    a.x += __shfl_xor(a.x, 32, 64); a.y += __shfl_xor(a.y, 32, 64);
    a.z += __shfl_xor(a.z, 32, 64); a.w += __shfl_xor(a.w, 32, 64);

    float inv = 1.0f / fmaxf((float)cnt, 1.0f);
    float4 ym = make_float4(a.x * inv, a.y * inv, a.z * inv, a.w * inv);

    float4 xv = x4[r * 16 + q];   // f32 x_dst; whole wave reads same 256B row

    if (es == 0) {
      colacc.x += ym.x; colacc.y += ym.y; colacc.z += ym.z; colacc.w += ym.w;
    }

    float hacc = bias;
    #pragma unroll
    for (int k = 0; k < DIM; ++k) {
      const int sl = k >> 2;  // es==0 lane holding quadrant k>>2
      float fx = __shfl((k & 3) == 0 ? xv.x : (k & 3) == 1 ? xv.y :
                        (k & 3) == 2 ? xv.z : xv.w, sl, 64);
      float fy = __shfl((k & 3) == 0 ? ym.x : (k & 3) == 1 ? ym.y :
                        (k & 3) == 2 ? ym.z : ym.w, sl, 64);
      hacc = fmaf(fx, Wt[k][lane], hacc);
      hacc = fmaf(fy, Wt[DIM + k][lane], hacc);
    }
    h[r * NCLS + lane] = hacc;
  }

  if (es == 0) {  // lane q owns columns 4q..4q+3
    colred[wv][q * 4 + 0] = colacc.x;
    colred[wv][q * 4 + 1] = colacc.y;
    colred[wv][q * 4 + 2] = colacc.z;
    colred[wv][q * 4 + 3] = colacc.w;
  }
  __syncthreads();
  if (tid < 64) {
    float s = colred[0][tid] + colred[1][tid] + colred[2][tid] + colred[3][tid];
    atomicAdd(&colsum[tid], s);
  }

  // ---- last-block reg-loss combine ----
  __syncthreads();
  if (tid == 0) {
    __threadfence();
    int old = atomicAdd(doneG, 1);
    lastFlag = (old == (int)gridDim.x - 1) ? 1 : 0;
  }
  __syncthreads();
  if (lastFlag && tid < 64) {
    const float inv_nd = 1.0f / (float)N_DSTC;
    float cs = atomicAdd(&colsum[tid], 0.0f);   // coherent atomic read
    float bv = atomicAdd(&regB[tid], 0.0f);
    float mx = cs * inv_nd;
    float p = fmaf((float)N_SRC * mx, mx, -2.0f * inv_nd * mx * bv);
    #pragma unroll
    for (int off = 32; off > 0; off >>= 1)
      p += __shfl_down(p, off, 64);
    if (tid == 0) {
      float av = atomicAdd(regA, 0.0f);
      float total = fmaf(av, inv_nd * inv_nd, p);
      out_scalar[0] = total * (1.0f / ((float)N_SRC * (float)NCLS));
    }
  }
}

// ---------------------------------------------------------------------------
extern "C" void kernel_launch(void* const* d_in, const int* in_sizes, int n_in,
                              void* d_out, int out_size, void* d_ws, size_t ws_size,
                              hipStream_t stream) {
  const float* x     = (const float*)d_in[0];
  // d_in[1] = w : dead (only ones_like(w) is used)
  const float* u_sum = (const float*)d_in[2];
  const float* Ww    = (const float*)d_in[3];
  const float* Wb    = (const float*)d_in[4];
  const int*   src   = (const int*)d_in[5];
  const int*   dst   = (const int*)d_in[6];

  float* out = (float*)d_out;
  int*   wsI = (int*)d_ws;

  int*   hist       = wsI;                        // 50000
  float* colsum     = (float*)(wsI + N_DSTC);     // 64
  float* regA       = colsum + 64;                // 1
  float* regB       = regA + 1;                   // 64
  int*   doneG      = (int*)(regB + 64);          // 1
  int*   blockSums  = doneG + 1;                  // 196
  int*   cursor     = blockSums + SCAN_NB;        // 50000
  int*   sorted_src = cursor + N_DSTC;            // 1,000,000
  uint2* xh2        = (uint2*)(wsI + 1100328);    // 16B-aligned bf16 x copy

  // zero: hist + colsum + regA + regB + doneG
  hipMemsetAsync(d_ws, 0, (size_t)(N_DSTC + 64 + 1 + 64 + 1) * sizeof(int), stream);

  hist_reg_kernel<<<HIST_BLOCKS + REG_BLOCKS, 256, 0, stream>>>(
      (const int4*)dst, x, u_sum, hist, regA, regB, xh2);
  scan_local  <<<SCAN_NB, 256, 0, stream>>>(hist, cursor, blockSums);
  scan_addoff <<<SCAN_NB, 256, 0, stream>>>(cursor, blockSums);
  reorder_kernel<<<(N_EDGES / 4 + 255) / 256, 256, 0, stream>>>(
      (const int4*)src, (const int4*)dst, cursor, sorted_src);
  gather_h    <<<GATHER_GRID, 256, 0, stream>>>(
      x, xh2, Ww, Wb, cursor, sorted_src, out, colsum, regA, regB, doneG,
      out + (size_t)N_DSTC * NCLS);
}